// Round 2
// baseline (464.450 us; speedup 1.0000x reference)
//
#include <hip/hip_runtime.h>

// DropBlock on (B,C,H,W)=(64,256,56,56), block_size=7, drop_prob=0.1
// mask_u is (B,C,50,50); gamma = 0.1/49 * 56^2/50^2.

#define BB 64
#define CC 256
#define HH 56
#define WW 56
#define HMM 50
#define WMM 50
#define BS 7

static constexpr unsigned int NPLANE = BB * CC;            // 16384
static constexpr unsigned int NTOT   = BB * CC * HH * WW;  // 51380224
static constexpr unsigned int NV     = NTOT / 4;           // 12845056 float4s
static constexpr unsigned int NP     = NV / 2;             // 6422528 32B units

typedef float f32x4 __attribute__((ext_vector_type(4)));

// One wave per (b,c) plane, 4 planes per 256-thread block.
// Fully unrolled: all 50 row-loads issue before the first ballot is consumed
// (one memory-latency pass instead of 10 serial rounds). No LDS, no barriers:
// the ballot result for row i is wave-uniform, so lane i keeps dilated row i
// in a register and the vertical 7-row OR is 3 shfl_up rounds (2->4->7).
__global__ void __launch_bounds__(256) dropblock_mask_kernel(
    const float* __restrict__ mask_u,
    unsigned long long* __restrict__ rowmask,
    unsigned int* __restrict__ plane_cnt,
    float gamma)
{
    const unsigned int wid   = threadIdx.x >> 6;
    const unsigned int lane  = threadIdx.x & 63u;
    const unsigned int plane = blockIdx.x * 4u + wid;
    const float* mu = mask_u + (size_t)plane * (HMM * WMM);

    unsigned long long my_d = 0ull;  // lane i holds horizontally-dilated row i

    #pragma unroll
    for (int i = 0; i < HMM; ++i) {
        float v = (lane < WMM) ? mu[i * WMM + lane] : 1.0f;  // 1.0 >= gamma -> bit 0
        unsigned long long m = __ballot(v < gamma);
        // horizontal dilation: OR of shifts 0..6
        unsigned long long d = m | (m << 1);  // {0,1}
        d |= d << 2;                          // {0..3}
        d |= d << 3;                          // {0..6}
        if (lane == (unsigned)i) my_d = d;
    }

    // vertical dilation: lane i needs OR of rows [i-6, i] (lanes >= 50 hold 0,
    // so rows 50..55 correctly get only the tail window; shfl_up for lane<delta
    // returns own value, which is idempotent under OR)
    unsigned long long blocked = my_d;
    blocked |= __shfl_up(blocked, 1, 64);  // window {0,1}
    blocked |= __shfl_up(blocked, 2, 64);  // window {0..3}
    blocked |= __shfl_up(blocked, 3, 64);  // window {0..6}

    if (lane < HH) rowmask[plane * HH + lane] = blocked;

    // dropped-pixel count for this plane (lanes >= 56 have blocked==0)
    unsigned int cnt = __popcll(blocked);
    #pragma unroll
    for (int off = 32; off > 0; off >>= 1)
        cnt += __shfl_down(cnt, off, 64);
    if (lane == 0) plane_cnt[plane] = cnt;
}

// Single-block reduction of the 16384 per-plane counts -> scale factor.
__global__ void __launch_bounds__(1024) dropblock_scale_kernel(
    const unsigned int* __restrict__ plane_cnt,
    float* __restrict__ scale_out)
{
    __shared__ unsigned int ssum[16];
    const unsigned int t = threadIdx.x;

    const uint4* pc4 = reinterpret_cast<const uint4*>(plane_cnt);  // 4096 uint4
    uint4 a = pc4[t];
    uint4 b = pc4[t + 1024];
    uint4 c = pc4[t + 2048];
    uint4 d = pc4[t + 3072];
    unsigned int s = a.x + a.y + a.z + a.w
                   + b.x + b.y + b.z + b.w
                   + c.x + c.y + c.z + c.w
                   + d.x + d.y + d.z + d.w;

    #pragma unroll
    for (int off = 32; off > 0; off >>= 1)
        s += __shfl_down(s, off, 64);
    if ((t & 63u) == 0u) ssum[t >> 6] = s;
    __syncthreads();

    if (t < 16) {
        unsigned int v = ssum[t];
        #pragma unroll
        for (int off = 8; off > 0; off >>= 1)
            v += __shfl_down(v, off, 64);
        if (t == 0) {
            // NTOT exactly representable in fp32; kept-count rounding error
            // <= 2 ulp -> scale rel err ~1e-7, way under threshold.
            *scale_out = (float)NTOT / (float)(NTOT - v);
        }
    }
}

// out = x * (dropped ? 0 : scale). One 32-byte unit (2 float4) per thread;
// 14 float4/row = 7 pairs, so a pair never crosses a mask row -> one rowmask
// load + one row/col computation per thread. Nontemporal on the 411 MB x/out
// streams keeps L2/L3 for rowmask.
__global__ void __launch_bounds__(256) dropblock_apply_kernel(
    const float* __restrict__ x,
    const unsigned long long* __restrict__ rowmask,
    const float* __restrict__ scale_ptr,
    float* __restrict__ out)
{
    const unsigned int p = blockIdx.x * 256u + threadIdx.x;  // 32B-unit index
    const float scale = *scale_ptr;  // uniform, precomputed

    // p -> (plane, row, pair) ; 392 pairs per plane, 7 per row
    unsigned int plane = p / 392u;
    unsigned int rem   = p - plane * 392u;
    unsigned int row   = rem / 7u;
    unsigned int pc    = rem - row * 7u;

    unsigned int rbits =
        (unsigned int)(rowmask[plane * HH + row] >> (pc * 8u)) & 0xffu;

    const f32x4* xp = reinterpret_cast<const f32x4*>(x) + (size_t)p * 2u;
    f32x4 a = __builtin_nontemporal_load(xp);
    f32x4 b = __builtin_nontemporal_load(xp + 1);

    f32x4 oa, ob;
    #pragma unroll
    for (int j = 0; j < 4; ++j)
        oa[j] = ((rbits >> j) & 1u) ? 0.0f : a[j] * scale;
    #pragma unroll
    for (int j = 0; j < 4; ++j)
        ob[j] = ((rbits >> (4 + j)) & 1u) ? 0.0f : b[j] * scale;

    f32x4* op = reinterpret_cast<f32x4*>(out) + (size_t)p * 2u;
    __builtin_nontemporal_store(oa, op);
    __builtin_nontemporal_store(ob, op + 1);
}

extern "C" void kernel_launch(void* const* d_in, const int* in_sizes, int n_in,
                              void* d_out, int out_size, void* d_ws, size_t ws_size,
                              hipStream_t stream) {
    const float* x      = (const float*)d_in[0];
    const float* mask_u = (const float*)d_in[1];
    float* out          = (float*)d_out;

    // ws layout (everything fully overwritten each call -> re-poison safe):
    //   [0, 64)           : scale (float, own cache line)
    //   [64, 64+65536)    : per-plane drop counts (16384 u32)
    //   [65600, +7340032) : 16384 planes * 56 rows * uint64 row bitmasks
    float* scale_ws             = (float*)d_ws;
    unsigned int* plane_cnt     = (unsigned int*)((char*)d_ws + 64);
    unsigned long long* rowmask = (unsigned long long*)((char*)d_ws + 65600);

    // gamma computed in double then cast to fp32, matching JAX's weak-typed
    // promotion of the Python float in (mask_u < gamma).
    const double gd = 0.1 / ((double)BS * BS) * ((double)HH * HH) /
                      (((double)HH - BS + 1.0) * ((double)HH - BS + 1.0));
    const float gamma = (float)gd;

    dropblock_mask_kernel<<<NPLANE / 4, 256, 0, stream>>>(
        mask_u, rowmask, plane_cnt, gamma);

    dropblock_scale_kernel<<<1, 1024, 0, stream>>>(plane_cnt, scale_ws);

    dropblock_apply_kernel<<<NP / 256u, 256, 0, stream>>>(
        x, rowmask, scale_ws, out);
}

// Round 3
// 454.759 us; speedup vs baseline: 1.0213x; 1.0213x over previous
//
#include <hip/hip_runtime.h>

// DropBlock on (B,C,H,W)=(64,256,56,56), block_size=7, drop_prob=0.1
// mask_u is (B,C,50,50); gamma = 0.1/49 * 56^2/50^2.

#define BB 64
#define CC 256
#define HH 56
#define WW 56
#define HMM 50
#define WMM 50
#define BS 7

static constexpr unsigned int NPLANE = BB * CC;            // 16384
static constexpr unsigned int NTOT   = BB * CC * HH * WW;  // 51380224
static constexpr unsigned int NV     = NTOT / 4;           // 12845056 float4s

// One wave per (b,c) plane, 4 planes per 256-thread block.
// Fully unrolled: all 50 row-loads issue before the first ballot is consumed
// (one memory-latency pass instead of 10 serial rounds). No LDS, no barriers:
// the ballot result for row i is wave-uniform, so lane i keeps dilated row i
// in a register and the vertical 7-row OR is 3 shfl_up rounds (2->4->7).
__global__ void __launch_bounds__(256) dropblock_mask_kernel(
    const float* __restrict__ mask_u,
    unsigned long long* __restrict__ rowmask,
    unsigned int* __restrict__ plane_cnt,
    float gamma)
{
    const unsigned int wid   = threadIdx.x >> 6;
    const unsigned int lane  = threadIdx.x & 63u;
    const unsigned int plane = blockIdx.x * 4u + wid;
    const float* mu = mask_u + (size_t)plane * (HMM * WMM);

    unsigned long long my_d = 0ull;  // lane i holds horizontally-dilated row i

    #pragma unroll
    for (int i = 0; i < HMM; ++i) {
        float v = (lane < WMM) ? mu[i * WMM + lane] : 1.0f;  // 1.0 >= gamma -> bit 0
        unsigned long long m = __ballot(v < gamma);
        // horizontal dilation: OR of shifts 0..6
        unsigned long long d = m | (m << 1);  // {0,1}
        d |= d << 2;                          // {0..3}
        d |= d << 3;                          // {0..6}
        if (lane == (unsigned)i) my_d = d;
    }

    // vertical dilation: lane i needs OR of rows [i-6, i] (lanes >= 50 hold 0,
    // so rows 50..55 correctly get only the tail window; shfl_up for lane<delta
    // returns own value, which is idempotent under OR)
    unsigned long long blocked = my_d;
    blocked |= __shfl_up(blocked, 1, 64);  // window {0,1}
    blocked |= __shfl_up(blocked, 2, 64);  // window {0..3}
    blocked |= __shfl_up(blocked, 3, 64);  // window {0..6}

    if (lane < HH) rowmask[plane * HH + lane] = blocked;

    // dropped-pixel count for this plane (lanes >= 56 have blocked==0)
    unsigned int cnt = __popcll(blocked);
    #pragma unroll
    for (int off = 32; off > 0; off >>= 1)
        cnt += __shfl_down(cnt, off, 64);
    if (lane == 0) plane_cnt[plane] = cnt;
}

// Single-block reduction of the 16384 per-plane counts -> scale factor.
__global__ void __launch_bounds__(1024) dropblock_scale_kernel(
    const unsigned int* __restrict__ plane_cnt,
    float* __restrict__ scale_out)
{
    __shared__ unsigned int ssum[16];
    const unsigned int t = threadIdx.x;

    const uint4* pc4 = reinterpret_cast<const uint4*>(plane_cnt);  // 4096 uint4
    uint4 a = pc4[t];
    uint4 b = pc4[t + 1024];
    uint4 c = pc4[t + 2048];
    uint4 d = pc4[t + 3072];
    unsigned int s = a.x + a.y + a.z + a.w
                   + b.x + b.y + b.z + b.w
                   + c.x + c.y + c.z + c.w
                   + d.x + d.y + d.z + d.w;

    #pragma unroll
    for (int off = 32; off > 0; off >>= 1)
        s += __shfl_down(s, off, 64);
    if ((t & 63u) == 0u) ssum[t >> 6] = s;
    __syncthreads();

    if (t < 16) {
        unsigned int v = ssum[t];
        #pragma unroll
        for (int off = 8; off > 0; off >>= 1)
            v += __shfl_down(v, off, 64);
        if (t == 0) {
            // NTOT exactly representable in fp32; kept-count rounding error
            // <= 2 ulp -> scale rel err ~1e-7, way under threshold.
            *scale_out = (float)NTOT / (float)(NTOT - v);
        }
    }
}

// float4 over the whole tensor: out = x * (dropped ? 0 : scale)
// (R1 form exactly: plain loads/stores, one float4 per thread — that config
// measured 455.5 total; the nt + 32B-pair variant was the R2 regression suspect.)
__global__ void __launch_bounds__(256) dropblock_apply_kernel(
    const float* __restrict__ x,
    const unsigned long long* __restrict__ rowmask,
    const float* __restrict__ scale_ptr,
    float* __restrict__ out)
{
    unsigned int idx = blockIdx.x * 256u + threadIdx.x;
    if (idx >= NV) return;

    const float scale = *scale_ptr;  // uniform scalar load, precomputed

    // idx -> (plane, row, col) ; 784 float4s per plane, 14 per row
    unsigned int plane = idx / (HH * WW / 4);            // / 784
    unsigned int rem   = idx - plane * (HH * WW / 4);
    unsigned int row   = rem / (WW / 4);                 // / 14
    unsigned int colv  = rem - row * (WW / 4);
    unsigned int col   = colv * 4;

    unsigned long long rm = rowmask[plane * HH + row];
    float4 xv = reinterpret_cast<const float4*>(x)[idx];
    float4 o;
    o.x = ((rm >> (col + 0)) & 1ull) ? 0.0f : xv.x * scale;
    o.y = ((rm >> (col + 1)) & 1ull) ? 0.0f : xv.y * scale;
    o.z = ((rm >> (col + 2)) & 1ull) ? 0.0f : xv.z * scale;
    o.w = ((rm >> (col + 3)) & 1ull) ? 0.0f : xv.w * scale;
    reinterpret_cast<float4*>(out)[idx] = o;
}

extern "C" void kernel_launch(void* const* d_in, const int* in_sizes, int n_in,
                              void* d_out, int out_size, void* d_ws, size_t ws_size,
                              hipStream_t stream) {
    const float* x      = (const float*)d_in[0];
    const float* mask_u = (const float*)d_in[1];
    float* out          = (float*)d_out;

    // ws layout (everything fully overwritten each call -> re-poison safe):
    //   [0, 64)           : scale (float, own cache line)
    //   [64, 64+65536)    : per-plane drop counts (16384 u32)
    //   [65600, +7340032) : 16384 planes * 56 rows * uint64 row bitmasks
    float* scale_ws             = (float*)d_ws;
    unsigned int* plane_cnt     = (unsigned int*)((char*)d_ws + 64);
    unsigned long long* rowmask = (unsigned long long*)((char*)d_ws + 65600);

    // gamma computed in double then cast to fp32, matching JAX's weak-typed
    // promotion of the Python float in (mask_u < gamma).
    const double gd = 0.1 / ((double)BS * BS) * ((double)HH * HH) /
                      (((double)HH - BS + 1.0) * ((double)HH - BS + 1.0));
    const float gamma = (float)gd;

    dropblock_mask_kernel<<<NPLANE / 4, 256, 0, stream>>>(
        mask_u, rowmask, plane_cnt, gamma);

    dropblock_scale_kernel<<<1, 1024, 0, stream>>>(plane_cnt, scale_ws);

    dropblock_apply_kernel<<<(NV + 255u) / 256u, 256, 0, stream>>>(
        x, rowmask, scale_ws, out);
}

// Round 4
// 433.664 us; speedup vs baseline: 1.0710x; 1.0486x over previous
//
#include <hip/hip_runtime.h>

// DropBlock on (B,C,H,W)=(64,256,56,56), block_size=7, drop_prob=0.1
// mask_u is (B,C,50,50); gamma = 0.1/49 * 56^2/50^2.

#define BB 64
#define CC 256
#define HH 56
#define WW 56
#define HMM 50
#define WMM 50
#define BS 7

static constexpr unsigned int NPLANE = BB * CC;            // 16384
static constexpr unsigned int NTOT   = BB * CC * HH * WW;  // 51380224
static constexpr unsigned int NV     = NTOT / 4;           // 12845056 float4s
static constexpr unsigned int PLANEF = HMM * WMM;          // 2500 floats/plane
static constexpr unsigned int PLANE4 = PLANEF / 4;         // 625 float4/plane

// 4 planes per 256-thread block. Phase 1: stage 4 planes (40 KB) into LDS via
// fully-coalesced float4 loads (the previous scalar-load version ran at
// 1.8 TB/s: 50 serial global_load_dword per lane, vmcnt-latency-bound).
// Phase 2 (per wave, from LDS): ballot -> 50-bit row mask, horizontal dilation
// by shifts, vertical dilation by 3 shfl_up rounds. No global atomics.
__global__ void __launch_bounds__(256) dropblock_mask_kernel(
    const float* __restrict__ mask_u,
    unsigned long long* __restrict__ rowmask,
    unsigned int* __restrict__ plane_cnt,
    float gamma)
{
    const unsigned int tid   = threadIdx.x;
    const unsigned int wid   = tid >> 6;
    const unsigned int lane  = tid & 63u;
    const unsigned int plane = blockIdx.x * 4u + wid;

    __shared__ float4 lds4[4 * PLANE4];  // 40 KB: 4 planes of raw mask_u
    const float* lds = reinterpret_cast<const float*>(lds4);

    // Phase 1: block-cooperative staging, 16 B/lane coalesced stream.
    {
        const float4* src = reinterpret_cast<const float4*>(mask_u)
                          + (size_t)blockIdx.x * (4 * PLANE4);
        #pragma unroll
        for (unsigned int r = 0; r < 10; ++r) {
            unsigned int idx = tid + r * 256u;
            if (idx < 4 * PLANE4) lds4[idx] = src[idx];
        }
    }
    __syncthreads();

    // Phase 2: per-wave ballot out of LDS (lanes 0..49 read consecutive words
    // of row i: <=2 lanes/bank aliasing, conflict-free).
    const float* mu = lds + wid * PLANEF;
    unsigned long long my_d = 0ull;  // lane i holds horizontally-dilated row i

    #pragma unroll
    for (int i = 0; i < HMM; ++i) {
        float v = (lane < WMM) ? mu[i * WMM + lane] : 1.0f;  // 1.0 >= gamma -> bit 0
        unsigned long long m = __ballot(v < gamma);
        // horizontal dilation: OR of shifts 0..6
        unsigned long long d = m | (m << 1);  // {0,1}
        d |= d << 2;                          // {0..3}
        d |= d << 3;                          // {0..6}
        if (lane == (unsigned)i) my_d = d;
    }

    // vertical dilation: lane i needs OR of rows [i-6, i] (lanes >= 50 hold 0,
    // so rows 50..55 correctly get only the tail window; shfl_up for lane<delta
    // returns own value, which is idempotent under OR)
    unsigned long long blocked = my_d;
    blocked |= __shfl_up(blocked, 1, 64);  // window {0,1}
    blocked |= __shfl_up(blocked, 2, 64);  // window {0..3}
    blocked |= __shfl_up(blocked, 3, 64);  // window {0..6}

    if (lane < HH) rowmask[plane * HH + lane] = blocked;

    // dropped-pixel count for this plane (lanes >= 56 have blocked==0)
    unsigned int cnt = __popcll(blocked);
    #pragma unroll
    for (int off = 32; off > 0; off >>= 1)
        cnt += __shfl_down(cnt, off, 64);
    if (lane == 0) plane_cnt[plane] = cnt;
}

// Single-block reduction of the 16384 per-plane counts -> scale factor.
__global__ void __launch_bounds__(1024) dropblock_scale_kernel(
    const unsigned int* __restrict__ plane_cnt,
    float* __restrict__ scale_out)
{
    __shared__ unsigned int ssum[16];
    const unsigned int t = threadIdx.x;

    const uint4* pc4 = reinterpret_cast<const uint4*>(plane_cnt);  // 4096 uint4
    uint4 a = pc4[t];
    uint4 b = pc4[t + 1024];
    uint4 c = pc4[t + 2048];
    uint4 d = pc4[t + 3072];
    unsigned int s = a.x + a.y + a.z + a.w
                   + b.x + b.y + b.z + b.w
                   + c.x + c.y + c.z + c.w
                   + d.x + d.y + d.z + d.w;

    #pragma unroll
    for (int off = 32; off > 0; off >>= 1)
        s += __shfl_down(s, off, 64);
    if ((t & 63u) == 0u) ssum[t >> 6] = s;
    __syncthreads();

    if (t < 16) {
        unsigned int v = ssum[t];
        #pragma unroll
        for (int off = 8; off > 0; off >>= 1)
            v += __shfl_down(v, off, 64);
        if (t == 0) {
            // NTOT exactly representable in fp32; kept-count rounding error
            // <= 2 ulp -> scale rel err ~1e-7, way under threshold.
            *scale_out = (float)NTOT / (float)(NTOT - v);
        }
    }
}

// float4 over the whole tensor: out = x * (dropped ? 0 : scale)
// (R1/R3 form exactly — 455 us baseline config; do not touch this round.)
__global__ void __launch_bounds__(256) dropblock_apply_kernel(
    const float* __restrict__ x,
    const unsigned long long* __restrict__ rowmask,
    const float* __restrict__ scale_ptr,
    float* __restrict__ out)
{
    unsigned int idx = blockIdx.x * 256u + threadIdx.x;
    if (idx >= NV) return;

    const float scale = *scale_ptr;  // uniform scalar load, precomputed

    // idx -> (plane, row, col) ; 784 float4s per plane, 14 per row
    unsigned int plane = idx / (HH * WW / 4);            // / 784
    unsigned int rem   = idx - plane * (HH * WW / 4);
    unsigned int row   = rem / (WW / 4);                 // / 14
    unsigned int colv  = rem - row * (WW / 4);
    unsigned int col   = colv * 4;

    unsigned long long rm = rowmask[plane * HH + row];
    float4 xv = reinterpret_cast<const float4*>(x)[idx];
    float4 o;
    o.x = ((rm >> (col + 0)) & 1ull) ? 0.0f : xv.x * scale;
    o.y = ((rm >> (col + 1)) & 1ull) ? 0.0f : xv.y * scale;
    o.z = ((rm >> (col + 2)) & 1ull) ? 0.0f : xv.z * scale;
    o.w = ((rm >> (col + 3)) & 1ull) ? 0.0f : xv.w * scale;
    reinterpret_cast<float4*>(out)[idx] = o;
}

extern "C" void kernel_launch(void* const* d_in, const int* in_sizes, int n_in,
                              void* d_out, int out_size, void* d_ws, size_t ws_size,
                              hipStream_t stream) {
    const float* x      = (const float*)d_in[0];
    const float* mask_u = (const float*)d_in[1];
    float* out          = (float*)d_out;

    // ws layout (everything fully overwritten each call -> re-poison safe):
    //   [0, 64)           : scale (float, own cache line)
    //   [64, 64+65536)    : per-plane drop counts (16384 u32)
    //   [65600, +7340032) : 16384 planes * 56 rows * uint64 row bitmasks
    float* scale_ws             = (float*)d_ws;
    unsigned int* plane_cnt     = (unsigned int*)((char*)d_ws + 64);
    unsigned long long* rowmask = (unsigned long long*)((char*)d_ws + 65600);

    // gamma computed in double then cast to fp32, matching JAX's weak-typed
    // promotion of the Python float in (mask_u < gamma).
    const double gd = 0.1 / ((double)BS * BS) * ((double)HH * HH) /
                      (((double)HH - BS + 1.0) * ((double)HH - BS + 1.0));
    const float gamma = (float)gd;

    dropblock_mask_kernel<<<NPLANE / 4, 256, 0, stream>>>(
        mask_u, rowmask, plane_cnt, gamma);

    dropblock_scale_kernel<<<1, 1024, 0, stream>>>(plane_cnt, scale_ws);

    dropblock_apply_kernel<<<(NV + 255u) / 256u, 256, 0, stream>>>(
        x, rowmask, scale_ws, out);
}